// Round 5
// baseline (129.404 us; speedup 1.0000x reference)
//
#include <hip/hip_runtime.h>
#include <math.h>

#define BN 1024
#define DN 256
#define HN 256
#define KN 8
typedef unsigned long long u64;

// ---------------- Kernel A: pairwise squared distances ----------------
// 64x64 tile per block, 256 threads, 4x4 register tile per thread.
// XOR-swizzled float4 LDS tiles (p = s ^ ((row>>2)&7)) keep the per-lane
// B-reads at 2-way bank aliasing (free). g-loop is software-pipelined:
// fragments for iteration g+1 are loaded while g computes, so the ~120cy
// LDS latency hides under the 128-FMA burst (critical at 1 wave/SIMD).
__global__ __launch_bounds__(256) void k_dist2(const float* __restrict__ x,
                                               float* __restrict__ dist2) {
  __shared__ float4 xi4[64][32];
  __shared__ float4 xj4[64][32];
  const int tid = threadIdx.x;
  const int tx = tid & 15, ty = tid >> 4;
  const int i0 = blockIdx.y << 6, j0 = blockIdx.x << 6;
  const int pim = ty & 7, pjm = tx & 7;
  float acc[4][4];
#pragma unroll
  for (int m = 0; m < 4; ++m)
#pragma unroll
    for (int n = 0; n < 4; ++n) acc[m][n] = 0.f;

  float4 A0[4], B0[4], A1[4], B1[4];

  auto loadg = [&](float4* Ad, float4* Bd, int g) {
    const int pi = g ^ pim, pj = g ^ pjm;
#pragma unroll
    for (int m = 0; m < 4; ++m) Ad[m] = xi4[(ty << 2) + m][pi];
#pragma unroll
    for (int n = 0; n < 4; ++n) Bd[n] = xj4[(tx << 2) + n][pj];
  };
  auto comp = [&](const float4* Ad, const float4* Bd) {
#pragma unroll
    for (int m = 0; m < 4; ++m)
#pragma unroll
      for (int n = 0; n < 4; ++n) {
        float t0 = Ad[m].x - Bd[n].x;
        float t1 = Ad[m].y - Bd[n].y;
        float t2 = Ad[m].z - Bd[n].z;
        float t3 = Ad[m].w - Bd[n].w;
        acc[m][n] = fmaf(t0, t0, acc[m][n]);
        acc[m][n] = fmaf(t1, t1, acc[m][n]);
        acc[m][n] = fmaf(t2, t2, acc[m][n]);
        acc[m][n] = fmaf(t3, t3, acc[m][n]);
      }
  };

  for (int c = 0; c < 2; ++c) {
    __syncthreads();
#pragma unroll
    for (int q = 0; q < 8; ++q) {
      int f = (q << 8) + tid;
      int row = f >> 5, s = f & 31;
      int p = s ^ ((row >> 2) & 7);
      xi4[row][p] = *reinterpret_cast<const float4*>(
          x + (size_t)(i0 + row) * DN + (c << 7) + (s << 2));
      xj4[row][p] = *reinterpret_cast<const float4*>(
          x + (size_t)(j0 + row) * DN + (c << 7) + (s << 2));
    }
    __syncthreads();

    loadg(A0, B0, 0);
    for (int g = 0; g < 32; g += 2) {
      loadg(A1, B1, g + 1);
      comp(A0, B0);
      loadg(A0, B0, (g + 2) & 31);  // wrap-load on last iter: discarded
      comp(A1, B1);
    }
  }
#pragma unroll
  for (int m = 0; m < 4; ++m) {
    float4 o;
    o.x = acc[m][0]; o.y = acc[m][1]; o.z = acc[m][2]; o.w = acc[m][3];
    *reinterpret_cast<float4*>(dist2 + (size_t)(i0 + (ty << 2) + m) * BN +
                               j0 + (tx << 2)) = o;
  }
}

// ---------------- Kernel B: per-row top-K (smallest) ----------------
// One WAVE per row, zero barriers. Key = (f32bits<<32)|j : non-negative
// floats order as uints, ties break toward smaller j (matches lax.top_k).
// Butterfly shfl_xor min (full-wave width=64) leaves the winner in every
// lane, so no broadcast step is needed.
__global__ __launch_bounds__(256) void k_topk(const float* __restrict__ dist2,
                                              int* __restrict__ topk) {
  const int lane = threadIdx.x & 63;
  const int wv = threadIdx.x >> 6;
  const int row = (blockIdx.x << 2) + wv;
  const float* base = dist2 + (size_t)row * BN;
  u64 key[16];
#pragma unroll
  for (int q = 0; q < 4; ++q) {
    int j = (q << 8) + (lane << 2);
    float4 v = *reinterpret_cast<const float4*>(base + j);
    key[q * 4 + 0] = ((u64)__float_as_uint(v.x) << 32) | (unsigned)(j + 0);
    key[q * 4 + 1] = ((u64)__float_as_uint(v.y) << 32) | (unsigned)(j + 1);
    key[q * 4 + 2] = ((u64)__float_as_uint(v.z) << 32) | (unsigned)(j + 2);
    key[q * 4 + 3] = ((u64)__float_as_uint(v.w) << 32) | (unsigned)(j + 3);
  }
  for (int r = 0; r < KN; ++r) {
    u64 m = key[0];
#pragma unroll
    for (int l = 1; l < 16; ++l) m = key[l] < m ? key[l] : m;
#pragma unroll
    for (int off = 32; off > 0; off >>= 1) {
      u64 o = __shfl_xor(m, off);
      m = o < m ? o : m;
    }
    if (lane == 0) topk[row * KN + r] = (int)(unsigned)(m & 0xffffffffull);
#pragma unroll
    for (int l = 0; l < 16; ++l)
      if (key[l] == m) key[l] = ~0ull;
  }
}

// ---------------- Kernel C: fused per-row epilogue ----------------
// 4 rows per block (grid 256): W rows read once per 4 output rows.
__global__ __launch_bounds__(256) void k_row(
    const float* __restrict__ x, const float* __restrict__ W_diff,
    const float* __restrict__ b_diff, const float* __restrict__ W_tau,
    const float* __restrict__ b_tau, const float* __restrict__ W_agg,
    const float* __restrict__ b_agg, const float* __restrict__ W_res,
    const float* __restrict__ b_res, const float* __restrict__ gamma,
    const float* __restrict__ beta, const int* __restrict__ topk,
    float* __restrict__ out) {
  const int tid = threadIdx.x;
  const int lane = tid & 63, wv = tid >> 6;
  const int r0 = blockIdx.x << 2;
  __shared__ float s_x[4][HN];
  __shared__ float s_s[4][HN];
  __shared__ float s_hk[4][HN];
  __shared__ float s_y[4][HN];
  __shared__ float s_tau[4];
  __shared__ float s_mu[4], s_rs[4];
  __shared__ int s_idx[4 * KN];

#pragma unroll
  for (int r = 0; r < 4; ++r) s_x[r][tid] = x[(size_t)(r0 + r) * DN + tid];
  if (tid < 4 * KN) s_idx[tid] = topk[r0 * KN + tid];
  __syncthreads();

  // sum of |x_i - x_j| over the K neighbors, per dimension
#pragma unroll
  for (int r = 0; r < 4; ++r) {
    float xv = s_x[r][tid];
    float s = 0.f;
#pragma unroll
    for (int k = 0; k < KN; ++k) {
      int j = s_idx[r * KN + k];
      s += fabsf(xv - x[(size_t)j * DN + tid]);
    }
    s_s[r][tid] = s;
  }
  // tau: wave wv reduces row wv
  {
    float p = 0.f;
#pragma unroll
    for (int q = 0; q < DN / 64; ++q) {
      int d = lane + (q << 6);
      p += s_x[wv][d] * W_tau[d];
    }
#pragma unroll
    for (int off = 32; off > 0; off >>= 1) p += __shfl_down(p, off);
    if (lane == 0) {
      float z = p + b_tau[0];
      float sp = z > 0.f ? z + log1pf(expf(-z)) : log1pf(expf(z));
      s_tau[wv] = fmaxf(sp, 0.01f) + 1.0f;
    }
  }
  __syncthreads();  // covers s_s and s_tau

  // matvec 1: h_k = (mean_k proj + b_diff) / tau
  {
    float a0 = 0.f, a1 = 0.f, a2 = 0.f, a3 = 0.f;
    const float* wrow = W_diff + (size_t)tid * DN;
#pragma unroll 8
    for (int d = 0; d < DN; d += 4) {
      float4 w4 = *reinterpret_cast<const float4*>(wrow + d);
      float4 s0 = *reinterpret_cast<const float4*>(&s_s[0][d]);
      float4 s1 = *reinterpret_cast<const float4*>(&s_s[1][d]);
      float4 s2 = *reinterpret_cast<const float4*>(&s_s[2][d]);
      float4 s3 = *reinterpret_cast<const float4*>(&s_s[3][d]);
      a0 += s0.x * w4.x + s0.y * w4.y + s0.z * w4.z + s0.w * w4.w;
      a1 += s1.x * w4.x + s1.y * w4.y + s1.z * w4.z + s1.w * w4.w;
      a2 += s2.x * w4.x + s2.y * w4.y + s2.z * w4.z + s2.w * w4.w;
      a3 += s3.x * w4.x + s3.y * w4.y + s3.z * w4.z + s3.w * w4.w;
    }
    float bd = b_diff[tid];
    s_hk[0][tid] = (a0 * 0.125f + bd) / s_tau[0];
    s_hk[1][tid] = (a1 * 0.125f + bd) / s_tau[1];
    s_hk[2][tid] = (a2 * 0.125f + bd) / s_tau[2];
    s_hk[3][tid] = (a3 * 0.125f + bd) / s_tau[3];
  }
  __syncthreads();

  // matvec 2 (W_agg on h_k) + matvec 3 (W_res on x), relu + residual
  {
    float a0 = 0.f, a1 = 0.f, a2 = 0.f, a3 = 0.f;
    float p0 = 0.f, p1 = 0.f, p2 = 0.f, p3 = 0.f;
    const float* wa = W_agg + (size_t)tid * HN;
    const float* wr = W_res + (size_t)tid * DN;
#pragma unroll 8
    for (int d = 0; d < DN; d += 4) {
      float4 va = *reinterpret_cast<const float4*>(wa + d);
      float4 vr = *reinterpret_cast<const float4*>(wr + d);
      float4 h0 = *reinterpret_cast<const float4*>(&s_hk[0][d]);
      float4 h1 = *reinterpret_cast<const float4*>(&s_hk[1][d]);
      float4 h2 = *reinterpret_cast<const float4*>(&s_hk[2][d]);
      float4 h3 = *reinterpret_cast<const float4*>(&s_hk[3][d]);
      float4 x0 = *reinterpret_cast<const float4*>(&s_x[0][d]);
      float4 x1 = *reinterpret_cast<const float4*>(&s_x[1][d]);
      float4 x2 = *reinterpret_cast<const float4*>(&s_x[2][d]);
      float4 x3 = *reinterpret_cast<const float4*>(&s_x[3][d]);
      a0 += h0.x * va.x + h0.y * va.y + h0.z * va.z + h0.w * va.w;
      a1 += h1.x * va.x + h1.y * va.y + h1.z * va.z + h1.w * va.w;
      a2 += h2.x * va.x + h2.y * va.y + h2.z * va.z + h2.w * va.w;
      a3 += h3.x * va.x + h3.y * va.y + h3.z * va.z + h3.w * va.w;
      p0 += x0.x * vr.x + x0.y * vr.y + x0.z * vr.z + x0.w * vr.w;
      p1 += x1.x * vr.x + x1.y * vr.y + x1.z * vr.z + x1.w * vr.w;
      p2 += x2.x * vr.x + x2.y * vr.y + x2.z * vr.z + x2.w * vr.w;
      p3 += x3.x * vr.x + x3.y * vr.y + x3.z * vr.z + x3.w * vr.w;
    }
    float ba = b_agg[tid], br = b_res[tid];
    s_y[0][tid] = fmaxf(a0 + ba, 0.f) + p0 + br;
    s_y[1][tid] = fmaxf(a1 + ba, 0.f) + p1 + br;
    s_y[2][tid] = fmaxf(a2 + ba, 0.f) + p2 + br;
    s_y[3][tid] = fmaxf(a3 + ba, 0.f) + p3 + br;
  }
  __syncthreads();

  // LayerNorm stats: wave wv reduces row wv
  {
    float sum = 0.f, sq = 0.f;
#pragma unroll
    for (int q = 0; q < HN / 64; ++q) {
      float v = s_y[wv][lane + (q << 6)];
      sum += v;
      sq += v * v;
    }
#pragma unroll
    for (int off = 32; off > 0; off >>= 1) {
      sum += __shfl_down(sum, off);
      sq += __shfl_down(sq, off);
    }
    if (lane == 0) {
      float mu = sum * (1.f / HN);
      float var = sq * (1.f / HN) - mu * mu;
      s_mu[wv] = mu;
      s_rs[wv] = 1.f / sqrtf(var + 1e-5f);
    }
  }
  __syncthreads();

  float g = gamma[tid], be = beta[tid];
#pragma unroll
  for (int r = 0; r < 4; ++r) {
    out[(size_t)(r0 + r) * HN + tid] =
        (s_y[r][tid] - s_mu[r]) * s_rs[r] * g + be;
  }
}

extern "C" void kernel_launch(void* const* d_in, const int* in_sizes, int n_in,
                              void* d_out, int out_size, void* d_ws,
                              size_t ws_size, hipStream_t stream) {
  const float* x = (const float*)d_in[0];
  const float* W_diff = (const float*)d_in[1];
  const float* b_diff = (const float*)d_in[2];
  const float* W_tau = (const float*)d_in[3];
  const float* b_tau = (const float*)d_in[4];
  const float* W_agg = (const float*)d_in[5];
  const float* b_agg = (const float*)d_in[6];
  const float* W_res = (const float*)d_in[7];
  const float* b_res = (const float*)d_in[8];
  const float* gamma = (const float*)d_in[9];
  const float* beta = (const float*)d_in[10];
  float* out = (float*)d_out;

  float* dist2 = (float*)d_ws;
  int* topk = (int*)((char*)d_ws + (size_t)BN * BN * sizeof(float));

  dim3 gA(BN / 64, BN / 64);
  k_dist2<<<gA, 256, 0, stream>>>(x, dist2);
  k_topk<<<BN / 4, 256, 0, stream>>>(dist2, topk);
  k_row<<<BN / 4, 256, 0, stream>>>(x, W_diff, b_diff, W_tau, b_tau, W_agg,
                                    b_agg, W_res, b_res, gamma, beta, topk,
                                    out);
}

// Round 6
// 127.849 us; speedup vs baseline: 1.0122x; 1.0122x over previous
//
#include <hip/hip_runtime.h>
#include <math.h>

#define BN 1024
#define DN 256
#define HN 256
#define KN 8
typedef unsigned long long u64;

// ---------------- Kernel A: pairwise squared distances ----------------
// 64x64 tile per block, 256 threads, 4x4 register tile per thread.
// XOR-swizzled float4 LDS tiles (p = s ^ ((row>>2)&7)): B-reads 2-way
// bank aliasing (free), A-reads 16-lane broadcast. Direct (sub+fma) d²,
// NOT the gram trick: gram's cancellation error (~1.5e-3) vs the fp32
// np-reference risks flipping the 8th/9th-neighbor selection; direct
// summation error (~5e-4) measured safe (absmax 0.0156).
__global__ __launch_bounds__(256) void k_dist2(const float* __restrict__ x,
                                               float* __restrict__ dist2) {
  __shared__ float4 xi4[64][32];
  __shared__ float4 xj4[64][32];
  const int tid = threadIdx.x;
  const int tx = tid & 15, ty = tid >> 4;
  const int i0 = blockIdx.y << 6, j0 = blockIdx.x << 6;
  const int pim = ty & 7, pjm = tx & 7;
  float acc[4][4];
#pragma unroll
  for (int m = 0; m < 4; ++m)
#pragma unroll
    for (int n = 0; n < 4; ++n) acc[m][n] = 0.f;

  float4 A0[4], B0[4], A1[4], B1[4];

  auto loadg = [&](float4* Ad, float4* Bd, int g) {
    const int pi = g ^ pim, pj = g ^ pjm;
#pragma unroll
    for (int m = 0; m < 4; ++m) Ad[m] = xi4[(ty << 2) + m][pi];
#pragma unroll
    for (int n = 0; n < 4; ++n) Bd[n] = xj4[(tx << 2) + n][pj];
  };
  auto comp = [&](const float4* Ad, const float4* Bd) {
#pragma unroll
    for (int m = 0; m < 4; ++m)
#pragma unroll
      for (int n = 0; n < 4; ++n) {
        float t0 = Ad[m].x - Bd[n].x;
        float t1 = Ad[m].y - Bd[n].y;
        float t2 = Ad[m].z - Bd[n].z;
        float t3 = Ad[m].w - Bd[n].w;
        acc[m][n] = fmaf(t0, t0, acc[m][n]);
        acc[m][n] = fmaf(t1, t1, acc[m][n]);
        acc[m][n] = fmaf(t2, t2, acc[m][n]);
        acc[m][n] = fmaf(t3, t3, acc[m][n]);
      }
  };

  for (int c = 0; c < 2; ++c) {
    __syncthreads();
#pragma unroll
    for (int q = 0; q < 8; ++q) {
      int f = (q << 8) + tid;
      int row = f >> 5, s = f & 31;
      int p = s ^ ((row >> 2) & 7);
      xi4[row][p] = *reinterpret_cast<const float4*>(
          x + (size_t)(i0 + row) * DN + (c << 7) + (s << 2));
      xj4[row][p] = *reinterpret_cast<const float4*>(
          x + (size_t)(j0 + row) * DN + (c << 7) + (s << 2));
    }
    __syncthreads();

    loadg(A0, B0, 0);
    for (int g = 0; g < 32; g += 2) {
      loadg(A1, B1, g + 1);
      comp(A0, B0);
      loadg(A0, B0, (g + 2) & 31);  // wrap-load on last iter: discarded
      comp(A1, B1);
    }
  }
#pragma unroll
  for (int m = 0; m < 4; ++m) {
    float4 o;
    o.x = acc[m][0]; o.y = acc[m][1]; o.z = acc[m][2]; o.w = acc[m][3];
    *reinterpret_cast<float4*>(dist2 + (size_t)(i0 + (ty << 2) + m) * BN +
                               j0 + (tx << 2)) = o;
  }
}

// ---------- Kernel B: fused top-K selection + per-row epilogue ----------
// Same 4-rows-per-block geometry as the old k_topk/k_row, fused:
// phase 1 (wave per row): top-8 by packed u64 key (f32bits<<32|j; floats
// >= 0 order as uints, ties -> lower j, matching lax.top_k), butterfly
// shfl_xor min (width 64) -> indices straight into LDS. The s_x staging
// loads are issued BEFORE phase 1 so their latency hides under it.
// phase 2: |diff| sums, tau, three matvecs, relu+residual, LayerNorm.
__global__ __launch_bounds__(256) void k_sel_row(
    const float* __restrict__ x, const float* __restrict__ W_diff,
    const float* __restrict__ b_diff, const float* __restrict__ W_tau,
    const float* __restrict__ b_tau, const float* __restrict__ W_agg,
    const float* __restrict__ b_agg, const float* __restrict__ W_res,
    const float* __restrict__ b_res, const float* __restrict__ gamma,
    const float* __restrict__ beta, const float* __restrict__ dist2,
    float* __restrict__ out) {
  const int tid = threadIdx.x;
  const int lane = tid & 63, wv = tid >> 6;
  const int r0 = blockIdx.x << 2;
  __shared__ float s_x[4][HN];
  __shared__ float s_s[4][HN];
  __shared__ float s_hk[4][HN];
  __shared__ float s_y[4][HN];
  __shared__ float s_tau[4];
  __shared__ float s_mu[4], s_rs[4];
  __shared__ int s_idx[4 * KN];

  // issue x staging early; consumed after the phase-1/2 barrier
#pragma unroll
  for (int r = 0; r < 4; ++r) s_x[r][tid] = x[(size_t)(r0 + r) * DN + tid];

  // ---- phase 1: top-8 for row r0+wv (one wave per row, no barriers) ----
  {
    const int row = r0 + wv;
    const float* base = dist2 + (size_t)row * BN;
    u64 key[16];
#pragma unroll
    for (int q = 0; q < 4; ++q) {
      int j = (q << 8) + (lane << 2);
      float4 v = *reinterpret_cast<const float4*>(base + j);
      key[q * 4 + 0] = ((u64)__float_as_uint(v.x) << 32) | (unsigned)(j + 0);
      key[q * 4 + 1] = ((u64)__float_as_uint(v.y) << 32) | (unsigned)(j + 1);
      key[q * 4 + 2] = ((u64)__float_as_uint(v.z) << 32) | (unsigned)(j + 2);
      key[q * 4 + 3] = ((u64)__float_as_uint(v.w) << 32) | (unsigned)(j + 3);
    }
    for (int r = 0; r < KN; ++r) {
      u64 m = key[0];
#pragma unroll
      for (int l = 1; l < 16; ++l) m = key[l] < m ? key[l] : m;
#pragma unroll
      for (int off = 32; off > 0; off >>= 1) {
        u64 o = __shfl_xor(m, off);
        m = o < m ? o : m;
      }
      if (lane == 0) s_idx[wv * KN + r] = (int)(unsigned)(m & 0xffffffffull);
#pragma unroll
      for (int l = 0; l < 16; ++l)
        if (key[l] == m) key[l] = ~0ull;
    }
  }
  __syncthreads();  // s_idx + s_x visible to all

  // ---- phase 2: per-row epilogue ----
  // sum of |x_i - x_j| over the K neighbors, per dimension
#pragma unroll
  for (int r = 0; r < 4; ++r) {
    float xv = s_x[r][tid];
    float s = 0.f;
#pragma unroll
    for (int k = 0; k < KN; ++k) {
      int j = s_idx[r * KN + k];
      s += fabsf(xv - x[(size_t)j * DN + tid]);
    }
    s_s[r][tid] = s;
  }
  // tau: wave wv reduces row wv
  {
    float p = 0.f;
#pragma unroll
    for (int q = 0; q < DN / 64; ++q) {
      int d = lane + (q << 6);
      p += s_x[wv][d] * W_tau[d];
    }
#pragma unroll
    for (int off = 32; off > 0; off >>= 1) p += __shfl_down(p, off);
    if (lane == 0) {
      float z = p + b_tau[0];
      float sp = z > 0.f ? z + log1pf(expf(-z)) : log1pf(expf(z));
      s_tau[wv] = fmaxf(sp, 0.01f) + 1.0f;
    }
  }
  __syncthreads();  // covers s_s and s_tau

  // matvec 1: h_k = (mean_k proj + b_diff) / tau
  {
    float a0 = 0.f, a1 = 0.f, a2 = 0.f, a3 = 0.f;
    const float* wrow = W_diff + (size_t)tid * DN;
#pragma unroll 8
    for (int d = 0; d < DN; d += 4) {
      float4 w4 = *reinterpret_cast<const float4*>(wrow + d);
      float4 s0 = *reinterpret_cast<const float4*>(&s_s[0][d]);
      float4 s1 = *reinterpret_cast<const float4*>(&s_s[1][d]);
      float4 s2 = *reinterpret_cast<const float4*>(&s_s[2][d]);
      float4 s3 = *reinterpret_cast<const float4*>(&s_s[3][d]);
      a0 += s0.x * w4.x + s0.y * w4.y + s0.z * w4.z + s0.w * w4.w;
      a1 += s1.x * w4.x + s1.y * w4.y + s1.z * w4.z + s1.w * w4.w;
      a2 += s2.x * w4.x + s2.y * w4.y + s2.z * w4.z + s2.w * w4.w;
      a3 += s3.x * w4.x + s3.y * w4.y + s3.z * w4.z + s3.w * w4.w;
    }
    float bd = b_diff[tid];
    s_hk[0][tid] = (a0 * 0.125f + bd) / s_tau[0];
    s_hk[1][tid] = (a1 * 0.125f + bd) / s_tau[1];
    s_hk[2][tid] = (a2 * 0.125f + bd) / s_tau[2];
    s_hk[3][tid] = (a3 * 0.125f + bd) / s_tau[3];
  }
  __syncthreads();

  // matvec 2 (W_agg on h_k) + matvec 3 (W_res on x), relu + residual
  {
    float a0 = 0.f, a1 = 0.f, a2 = 0.f, a3 = 0.f;
    float p0 = 0.f, p1 = 0.f, p2 = 0.f, p3 = 0.f;
    const float* wa = W_agg + (size_t)tid * HN;
    const float* wr = W_res + (size_t)tid * DN;
#pragma unroll 8
    for (int d = 0; d < DN; d += 4) {
      float4 va = *reinterpret_cast<const float4*>(wa + d);
      float4 vr = *reinterpret_cast<const float4*>(wr + d);
      float4 h0 = *reinterpret_cast<const float4*>(&s_hk[0][d]);
      float4 h1 = *reinterpret_cast<const float4*>(&s_hk[1][d]);
      float4 h2 = *reinterpret_cast<const float4*>(&s_hk[2][d]);
      float4 h3 = *reinterpret_cast<const float4*>(&s_hk[3][d]);
      float4 x0 = *reinterpret_cast<const float4*>(&s_x[0][d]);
      float4 x1 = *reinterpret_cast<const float4*>(&s_x[1][d]);
      float4 x2 = *reinterpret_cast<const float4*>(&s_x[2][d]);
      float4 x3 = *reinterpret_cast<const float4*>(&s_x[3][d]);
      a0 += h0.x * va.x + h0.y * va.y + h0.z * va.z + h0.w * va.w;
      a1 += h1.x * va.x + h1.y * va.y + h1.z * va.z + h1.w * va.w;
      a2 += h2.x * va.x + h2.y * va.y + h2.z * va.z + h2.w * va.w;
      a3 += h3.x * va.x + h3.y * va.y + h3.z * va.z + h3.w * va.w;
      p0 += x0.x * vr.x + x0.y * vr.y + x0.z * vr.z + x0.w * vr.w;
      p1 += x1.x * vr.x + x1.y * vr.y + x1.z * vr.z + x1.w * vr.w;
      p2 += x2.x * vr.x + x2.y * vr.y + x2.z * vr.z + x2.w * vr.w;
      p3 += x3.x * vr.x + x3.y * vr.y + x3.z * vr.z + x3.w * vr.w;
    }
    float ba = b_agg[tid], br = b_res[tid];
    s_y[0][tid] = fmaxf(a0 + ba, 0.f) + p0 + br;
    s_y[1][tid] = fmaxf(a1 + ba, 0.f) + p1 + br;
    s_y[2][tid] = fmaxf(a2 + ba, 0.f) + p2 + br;
    s_y[3][tid] = fmaxf(a3 + ba, 0.f) + p3 + br;
  }
  __syncthreads();

  // LayerNorm stats: wave wv reduces row wv
  {
    float sum = 0.f, sq = 0.f;
#pragma unroll
    for (int q = 0; q < HN / 64; ++q) {
      float v = s_y[wv][lane + (q << 6)];
      sum += v;
      sq += v * v;
    }
#pragma unroll
    for (int off = 32; off > 0; off >>= 1) {
      sum += __shfl_down(sum, off);
      sq += __shfl_down(sq, off);
    }
    if (lane == 0) {
      float mu = sum * (1.f / HN);
      float var = sq * (1.f / HN) - mu * mu;
      s_mu[wv] = mu;
      s_rs[wv] = 1.f / sqrtf(var + 1e-5f);
    }
  }
  __syncthreads();

  float g = gamma[tid], be = beta[tid];
#pragma unroll
  for (int r = 0; r < 4; ++r) {
    out[(size_t)(r0 + r) * HN + tid] =
        (s_y[r][tid] - s_mu[r]) * s_rs[r] * g + be;
  }
}

extern "C" void kernel_launch(void* const* d_in, const int* in_sizes, int n_in,
                              void* d_out, int out_size, void* d_ws,
                              size_t ws_size, hipStream_t stream) {
  const float* x = (const float*)d_in[0];
  const float* W_diff = (const float*)d_in[1];
  const float* b_diff = (const float*)d_in[2];
  const float* W_tau = (const float*)d_in[3];
  const float* b_tau = (const float*)d_in[4];
  const float* W_agg = (const float*)d_in[5];
  const float* b_agg = (const float*)d_in[6];
  const float* W_res = (const float*)d_in[7];
  const float* b_res = (const float*)d_in[8];
  const float* gamma = (const float*)d_in[9];
  const float* beta = (const float*)d_in[10];
  float* out = (float*)d_out;

  float* dist2 = (float*)d_ws;

  dim3 gA(BN / 64, BN / 64);
  k_dist2<<<gA, 256, 0, stream>>>(x, dist2);
  k_sel_row<<<BN / 4, 256, 0, stream>>>(x, W_diff, b_diff, W_tau, b_tau,
                                        W_agg, b_agg, W_res, b_res, gamma,
                                        beta, dist2, out);
}

// Round 7
// 120.156 us; speedup vs baseline: 1.0770x; 1.0640x over previous
//
#include <hip/hip_runtime.h>
#include <math.h>

#define BN 1024
#define DN 256
#define HN 256
#define KN 8
#define SP 260  // padded row stride (floats) for per-row LDS vectors
typedef unsigned long long u64;

// ---------------- Kernel A: pairwise squared distances ----------------
// UNCHANGED (bit-identical dist2 -> identical top-k selection).
__global__ __launch_bounds__(256) void k_dist2(const float* __restrict__ x,
                                               float* __restrict__ dist2) {
  __shared__ float4 xi4[64][32];
  __shared__ float4 xj4[64][32];
  const int tid = threadIdx.x;
  const int tx = tid & 15, ty = tid >> 4;
  const int i0 = blockIdx.y << 6, j0 = blockIdx.x << 6;
  const int pim = ty & 7, pjm = tx & 7;
  float acc[4][4];
#pragma unroll
  for (int m = 0; m < 4; ++m)
#pragma unroll
    for (int n = 0; n < 4; ++n) acc[m][n] = 0.f;

  float4 A0[4], B0[4], A1[4], B1[4];

  auto loadg = [&](float4* Ad, float4* Bd, int g) {
    const int pi = g ^ pim, pj = g ^ pjm;
#pragma unroll
    for (int m = 0; m < 4; ++m) Ad[m] = xi4[(ty << 2) + m][pi];
#pragma unroll
    for (int n = 0; n < 4; ++n) Bd[n] = xj4[(tx << 2) + n][pj];
  };
  auto comp = [&](const float4* Ad, const float4* Bd) {
#pragma unroll
    for (int m = 0; m < 4; ++m)
#pragma unroll
      for (int n = 0; n < 4; ++n) {
        float t0 = Ad[m].x - Bd[n].x;
        float t1 = Ad[m].y - Bd[n].y;
        float t2 = Ad[m].z - Bd[n].z;
        float t3 = Ad[m].w - Bd[n].w;
        acc[m][n] = fmaf(t0, t0, acc[m][n]);
        acc[m][n] = fmaf(t1, t1, acc[m][n]);
        acc[m][n] = fmaf(t2, t2, acc[m][n]);
        acc[m][n] = fmaf(t3, t3, acc[m][n]);
      }
  };

  for (int c = 0; c < 2; ++c) {
    __syncthreads();
#pragma unroll
    for (int q = 0; q < 8; ++q) {
      int f = (q << 8) + tid;
      int row = f >> 5, s = f & 31;
      int p = s ^ ((row >> 2) & 7);
      xi4[row][p] = *reinterpret_cast<const float4*>(
          x + (size_t)(i0 + row) * DN + (c << 7) + (s << 2));
      xj4[row][p] = *reinterpret_cast<const float4*>(
          x + (size_t)(j0 + row) * DN + (c << 7) + (s << 2));
    }
    __syncthreads();

    loadg(A0, B0, 0);
    for (int g = 0; g < 32; g += 2) {
      loadg(A1, B1, g + 1);
      comp(A0, B0);
      loadg(A0, B0, (g + 2) & 31);
      comp(A1, B1);
    }
  }
#pragma unroll
  for (int m = 0; m < 4; ++m) {
    float4 o;
    o.x = acc[m][0]; o.y = acc[m][1]; o.z = acc[m][2]; o.w = acc[m][3];
    *reinterpret_cast<float4*>(dist2 + (size_t)(i0 + (ty << 2) + m) * BN +
                               j0 + (tx << 2)) = o;
  }
}

// ---------- Kernel B: fused top-K + epilogue, coalesced strip-dot matvecs ----
// Matvec redesign: lane l owns d-strip [4l,4l+4). Per output row h, ONE
// float4 load at W + h*256 + 4l -> the wave's 64 lanes form one contiguous
// 1 KB request (vs the old per-lane-row reads: 64 distinct lines/instr).
// Partial dots combine via a static-index butterfly reduce-scatter:
// lane ends with the full dot for (j=(lane&31)>>2, r=lane&3). 3 VALU per
// output, no LDS staging, no barriers inside a pass.
__global__ __launch_bounds__(256) void k_sel_row(
    const float* __restrict__ x, const float* __restrict__ W_diff,
    const float* __restrict__ b_diff, const float* __restrict__ W_tau,
    const float* __restrict__ b_tau, const float* __restrict__ W_agg,
    const float* __restrict__ b_agg, const float* __restrict__ W_res,
    const float* __restrict__ b_res, const float* __restrict__ gamma,
    const float* __restrict__ beta, const float* __restrict__ dist2,
    float* __restrict__ out) {
  const int tid = threadIdx.x;
  const int lane = tid & 63, wv = tid >> 6;
  const int r0 = blockIdx.x << 2;
  __shared__ float s_x[4 * SP];
  __shared__ float s_s[4 * SP];
  __shared__ float s_hk[4 * SP];
  __shared__ float s_y[4 * SP];
  __shared__ float s_tau[4];
  __shared__ float s_mu[4], s_rs[4];
  __shared__ int s_idx[4 * KN];

  // stage x rows (consumed after the phase-1 barrier)
#pragma unroll
  for (int r = 0; r < 4; ++r)
    s_x[r * SP + tid] = x[(size_t)(r0 + r) * DN + tid];

  // ---- phase 1: top-8 for row r0+wv (one wave per row, no barriers) ----
  {
    const int row = r0 + wv;
    const float* base = dist2 + (size_t)row * BN;
    u64 key[16];
#pragma unroll
    for (int q = 0; q < 4; ++q) {
      int j = (q << 8) + (lane << 2);
      float4 v = *reinterpret_cast<const float4*>(base + j);
      key[q * 4 + 0] = ((u64)__float_as_uint(v.x) << 32) | (unsigned)(j + 0);
      key[q * 4 + 1] = ((u64)__float_as_uint(v.y) << 32) | (unsigned)(j + 1);
      key[q * 4 + 2] = ((u64)__float_as_uint(v.z) << 32) | (unsigned)(j + 2);
      key[q * 4 + 3] = ((u64)__float_as_uint(v.w) << 32) | (unsigned)(j + 3);
    }
    for (int r = 0; r < KN; ++r) {
      u64 m = key[0];
#pragma unroll
      for (int l = 1; l < 16; ++l) m = key[l] < m ? key[l] : m;
#pragma unroll
      for (int off = 32; off > 0; off >>= 1) {
        u64 o = __shfl_xor(m, off);
        m = o < m ? o : m;
      }
      if (lane == 0) s_idx[wv * KN + r] = (int)(unsigned)(m & 0xffffffffull);
#pragma unroll
      for (int l = 0; l < 16; ++l)
        if (key[l] == m) key[l] = ~0ull;
    }
  }
  __syncthreads();  // s_idx + s_x visible

  // ---- |diff| sums over the K neighbors ----
#pragma unroll
  for (int r = 0; r < 4; ++r) {
    float xv = s_x[r * SP + tid];
    float s = 0.f;
#pragma unroll
    for (int k = 0; k < KN; ++k) {
      int j = s_idx[r * KN + k];
      s += fabsf(xv - x[(size_t)j * DN + tid]);
    }
    s_s[r * SP + tid] = s;
  }
  // ---- tau: wave wv reduces row wv ----
  {
    float p = 0.f;
#pragma unroll
    for (int q = 0; q < DN / 64; ++q) {
      int d = lane + (q << 6);
      p += s_x[wv * SP + d] * W_tau[d];
    }
#pragma unroll
    for (int off = 32; off > 0; off >>= 1) p += __shfl_down(p, off);
    if (lane == 0) {
      float z = p + b_tau[0];
      float sp = z > 0.f ? z + log1pf(expf(-z)) : log1pf(expf(z));
      s_tau[wv] = fmaxf(sp, 0.01f) + 1.0f;
    }
  }
  __syncthreads();  // covers s_s and s_tau

  // ---- matvec passes: coalesced strip-dot ----
  auto ldchunk = [&](float4* g, const float* W, int hb) {
#pragma unroll
    for (int j = 0; j < 8; ++j)
      g[j] = *reinterpret_cast<const float4*>(W + ((size_t)(hb + j) << 8) +
                                              (lane << 2));
  };
  // 8-h chunk dot vs strip-registers sv[4]; returns full dot for
  // (j=(lane&31)>>2, r=lane&3) via butterfly reduce-scatter.
  auto dotchunk = [&](const float4* w, const float4* sv) -> float {
    float v32[32];
#pragma unroll
    for (int j = 0; j < 8; ++j)
#pragma unroll
      for (int r = 0; r < 4; ++r) {
        float a = w[j].x * sv[r].x;
        a = fmaf(w[j].y, sv[r].y, a);
        a = fmaf(w[j].z, sv[r].z, a);
        a = fmaf(w[j].w, sv[r].w, a);
        v32[j * 4 + r] = a;
      }
    float v16[16], v8[8], v4[4], v2[2], vf;
#pragma unroll
    for (int m = 0; m < 16; ++m) {
      float keep = (lane & 1) ? v32[2 * m + 1] : v32[2 * m];
      float send = (lane & 1) ? v32[2 * m] : v32[2 * m + 1];
      v16[m] = keep + __shfl_xor(send, 1);
    }
#pragma unroll
    for (int m = 0; m < 8; ++m) {
      float keep = (lane & 2) ? v16[2 * m + 1] : v16[2 * m];
      float send = (lane & 2) ? v16[2 * m] : v16[2 * m + 1];
      v8[m] = keep + __shfl_xor(send, 2);
    }
#pragma unroll
    for (int m = 0; m < 4; ++m) {
      float keep = (lane & 4) ? v8[2 * m + 1] : v8[2 * m];
      float send = (lane & 4) ? v8[2 * m] : v8[2 * m + 1];
      v4[m] = keep + __shfl_xor(send, 4);
    }
#pragma unroll
    for (int m = 0; m < 2; ++m) {
      float keep = (lane & 8) ? v4[2 * m + 1] : v4[2 * m];
      float send = (lane & 8) ? v4[2 * m] : v4[2 * m + 1];
      v2[m] = keep + __shfl_xor(send, 8);
    }
    {
      float keep = (lane & 16) ? v2[1] : v2[0];
      float send = (lane & 16) ? v2[0] : v2[1];
      vf = keep + __shfl_xor(send, 16);
    }
    vf += __shfl_xor(vf, 32);  // sum halves; lanes l, l+32 now duplicate
    return vf;
  };

  const int oj = (lane & 31) >> 2;  // output h-offset within chunk
  const int orr = lane & 3;         // output r

  // pass A: W_diff -> s_hk
  {
    float4 sA[4];
#pragma unroll
    for (int r = 0; r < 4; ++r)
      sA[r] = *reinterpret_cast<const float4*>(&s_s[r * SP + (lane << 2)]);
    float4 g[8];
    ldchunk(g, W_diff, wv << 6);
#pragma unroll
    for (int s = 0; s < 8; ++s) {
      float4 w[8];
#pragma unroll
      for (int j = 0; j < 8; ++j) w[j] = g[j];
      if (s < 7) ldchunk(g, W_diff, (wv << 6) + ((s + 1) << 3));
      float vf = dotchunk(w, sA);
      int h = (wv << 6) + (s << 3) + oj;
      s_hk[orr * SP + h] = (vf * 0.125f + b_diff[h]) / s_tau[orr];
    }
  }
  __syncthreads();  // s_hk complete

  // pass B: W_agg (on h_k) then W_res (on x); relu + residual -> s_y
  {
    float4 sH[4], sX[4];
#pragma unroll
    for (int r = 0; r < 4; ++r) {
      sH[r] = *reinterpret_cast<const float4*>(&s_hk[r * SP + (lane << 2)]);
      sX[r] = *reinterpret_cast<const float4*>(&s_x[r * SP + (lane << 2)]);
    }
    float aggv[8];
    float4 g[8];
    ldchunk(g, W_agg, wv << 6);
#pragma unroll
    for (int s = 0; s < 8; ++s) {
      float4 w[8];
#pragma unroll
      for (int j = 0; j < 8; ++j) w[j] = g[j];
      if (s < 7) ldchunk(g, W_agg, (wv << 6) + ((s + 1) << 3));
      aggv[s] = dotchunk(w, sH);
    }
    ldchunk(g, W_res, wv << 6);
#pragma unroll
    for (int s = 0; s < 8; ++s) {
      float4 w[8];
#pragma unroll
      for (int j = 0; j < 8; ++j) w[j] = g[j];
      if (s < 7) ldchunk(g, W_res, (wv << 6) + ((s + 1) << 3));
      float resv = dotchunk(w, sX);
      int h = (wv << 6) + (s << 3) + oj;
      float yv = fmaxf(aggv[s] + b_agg[h], 0.f) + resv + b_res[h];
      s_y[orr * SP + h] = yv;
    }
  }
  __syncthreads();

  // ---- LayerNorm: wave wv reduces row wv ----
  {
    float sum = 0.f, sq = 0.f;
#pragma unroll
    for (int q = 0; q < HN / 64; ++q) {
      float v = s_y[wv * SP + lane + (q << 6)];
      sum += v;
      sq += v * v;
    }
#pragma unroll
    for (int off = 32; off > 0; off >>= 1) {
      sum += __shfl_down(sum, off);
      sq += __shfl_down(sq, off);
    }
    if (lane == 0) {
      float mu = sum * (1.f / HN);
      float var = sq * (1.f / HN) - mu * mu;
      s_mu[wv] = mu;
      s_rs[wv] = 1.f / sqrtf(var + 1e-5f);
    }
  }
  __syncthreads();

  float g = gamma[tid], be = beta[tid];
#pragma unroll
  for (int r = 0; r < 4; ++r) {
    out[(size_t)(r0 + r) * HN + tid] =
        (s_y[r * SP + tid] - s_mu[r]) * s_rs[r] * g + be;
  }
}

extern "C" void kernel_launch(void* const* d_in, const int* in_sizes, int n_in,
                              void* d_out, int out_size, void* d_ws,
                              size_t ws_size, hipStream_t stream) {
  const float* x = (const float*)d_in[0];
  const float* W_diff = (const float*)d_in[1];
  const float* b_diff = (const float*)d_in[2];
  const float* W_tau = (const float*)d_in[3];
  const float* b_tau = (const float*)d_in[4];
  const float* W_agg = (const float*)d_in[5];
  const float* b_agg = (const float*)d_in[6];
  const float* W_res = (const float*)d_in[7];
  const float* b_res = (const float*)d_in[8];
  const float* gamma = (const float*)d_in[9];
  const float* beta = (const float*)d_in[10];
  float* out = (float*)d_out;

  float* dist2 = (float*)d_ws;

  dim3 gA(BN / 64, BN / 64);
  k_dist2<<<gA, 256, 0, stream>>>(x, dist2);
  k_sel_row<<<BN / 4, 256, 0, stream>>>(x, W_diff, b_diff, W_tau, b_tau,
                                        W_agg, b_agg, W_res, b_res, gamma,
                                        beta, dist2, out);
}